// Round 8
// baseline (565.290 us; speedup 1.0000x reference)
//
#include <hip/hip_runtime.h>

#define VOCAB 128
#define EMB   10
#define HID   20
#define BATCH 256
#define TLEN  2048
// tanh(x) = 1 - 2/(exp(2x)+1); v_exp_f32 computes 2^z, so fold 2*log2(e)
// into the weights/tables:  z = PRESCALE * (xw + W_hh h)
// RECURRENCE IS CARRIED IN r = 1/(2^z + 1)  (h = 1 - 2r):
//   z_j = [P(tok)_j] + sum_k (-2*PRESCALE*W_hh[j,k]) * r_k
// where P already contains PRESCALE*(biases + emb.W_ih + sum_k W_hh[j,k]).
// Consumers fold h=1-2r into their weights: out = (b+sum_j Wout) - 2*Wout.r
#define PRESCALE 2.8853900817779268f

// ---------------------------------------------------------------------------
// Kernel A: P[v][j] = PRESCALE*(b_ih[j]+b_hh[j]+sum_e W_ih[j,e]*emb[v,e]
//                              + sum_k W_hh[j,k])
// ---------------------------------------------------------------------------
__global__ __launch_bounds__(256)
void build_table(const float* __restrict__ emb, const float* __restrict__ W_ih,
                 const float* __restrict__ W_hh,
                 const float* __restrict__ b_ih, const float* __restrict__ b_hh,
                 float* __restrict__ P) {
    int idx = blockIdx.x * blockDim.x + threadIdx.x;
    if (idx < VOCAB * HID) {
        int v = idx / HID, j = idx % HID;
        float acc = b_ih[j] + b_hh[j];
        #pragma unroll
        for (int e = 0; e < EMB; ++e)
            acc = fmaf(W_ih[j * EMB + e], emb[v * EMB + e], acc);
        float wsum = 0.f;
        #pragma unroll
        for (int k = 0; k < HID; ++k) wsum += W_hh[j * HID + k];
        P[idx] = (acc + wsum) * PRESCALE;
    }
}

// ---------------------------------------------------------------------------
// Fused kernel: one block per TWO batch rows, 4 waves. LDS kept < 64 KiB.
//   wave 0  : TWO independent recurrence chains interleaved in one
//             instruction stream: lanes 0-19 carry row A's state, lanes
//             32-51 carry row B's. Chain A's dependency bubbles (readlane
//             hazard, 5-deep fma chain, exp2/rcp latency) are filled by
//             chain B's instructions. Broadcasts: readlane(rA,k) and
//             readlane(rB,32+k). SHARED hbuf: lane l<32 stores rA at col l
//             (valid 0-19), lane l>=32 stores rB at col l (valid 32-51);
//             garbage lanes write their own unused columns. One v_cndmask
//             per store, off the critical chain.
//   waves1-3: consume chunk c-1 of both rows (128 t-rows) while wave 0
//             produces chunk c.
// ---------------------------------------------------------------------------
#define RNN_STEP2(XWA, XWB) { \
    const int riA_ = __float_as_int(rA); \
    const int riB_ = __float_as_int(rB); \
    float aA0 = (XWA), aA1 = 0.f, aA2 = 0.f, aA3 = 0.f; \
    float aB0 = (XWB), aB1 = 0.f, aB2 = 0.f, aB3 = 0.f; \
    _Pragma("unroll") \
    for (int k = 0; k < HID; k += 4) { \
        float cA0 = __int_as_float(__builtin_amdgcn_readlane(riA_, k + 0)); \
        float cB0 = __int_as_float(__builtin_amdgcn_readlane(riB_, 32 + k + 0)); \
        float cA1 = __int_as_float(__builtin_amdgcn_readlane(riA_, k + 1)); \
        float cB1 = __int_as_float(__builtin_amdgcn_readlane(riB_, 32 + k + 1)); \
        float cA2 = __int_as_float(__builtin_amdgcn_readlane(riA_, k + 2)); \
        float cB2 = __int_as_float(__builtin_amdgcn_readlane(riB_, 32 + k + 2)); \
        float cA3 = __int_as_float(__builtin_amdgcn_readlane(riA_, k + 3)); \
        float cB3 = __int_as_float(__builtin_amdgcn_readlane(riB_, 32 + k + 3)); \
        aA0 = fmaf(w[k + 0], cA0, aA0); aB0 = fmaf(w[k + 0], cB0, aB0); \
        aA1 = fmaf(w[k + 1], cA1, aA1); aB1 = fmaf(w[k + 1], cB1, aB1); \
        aA2 = fmaf(w[k + 2], cA2, aA2); aB2 = fmaf(w[k + 2], cB2, aB2); \
        aA3 = fmaf(w[k + 3], cA3, aA3); aB3 = fmaf(w[k + 3], cB3, aB3); } \
    float zA_ = (aA0 + aA1) + (aA2 + aA3); \
    float zB_ = (aB0 + aB1) + (aB2 + aB3); \
    float uA_ = __builtin_amdgcn_exp2f(zA_); \
    float uB_ = __builtin_amdgcn_exp2f(zB_); \
    rA = __builtin_amdgcn_rcpf(uA_ + 1.0f); \
    rB = __builtin_amdgcn_rcpf(uB_ + 1.0f); }

__global__ __launch_bounds__(256)
void rnn_fused(const int* __restrict__ tokens, const float* __restrict__ W_hh,
               const float* __restrict__ P, const float* __restrict__ W_out,
               const float* __restrict__ b_out, float* __restrict__ out) {
    __shared__ float Pl[VOCAB * HID];                 // 10240 B
    __shared__ __align__(16) int tokA[TLEN + 16];     //  8256 B
    __shared__ __align__(16) int tokB[TLEN + 16];     //  8256 B
    __shared__ float hbuf[2][64][64];                 // 32768 B shared by BOTH
                                                      // chains: A cols 0-19,
                                                      // B cols 32-51
    // total static LDS: 59520 B (< 64 KiB)
    const int tid  = threadIdx.x;
    const int lane = tid & 63;
    const int wid  = tid >> 6;
    const int blk  = blockIdx.x;
    const int bA   = 2 * blk, bB = 2 * blk + 1;

    // cooperative staging (all 256 threads)
    for (int i = tid; i < VOCAB * HID; i += 256) Pl[i] = P[i];
    const int4* srcA = (const int4*)(tokens + (size_t)bA * TLEN);
    const int4* srcB = (const int4*)(tokens + (size_t)bB * TLEN);
    int4* dA = (int4*)tokA;
    int4* dB = (int4*)tokB;
    for (int i = tid; i < TLEN / 4; i += 256) { dA[i] = srcA[i]; dB[i] = srcB[i]; }
    if (tid < 16) { tokA[TLEN + tid] = 0; tokB[TLEN + tid] = 0; }

    // per-role register init (before the staging barrier: global reads only)
    const int j = (lane & 31) < HID ? (lane & 31) : HID - 1;  // clamp: dup row 19
    const bool loHalf = lane < 32;
    float w[HID], wB[HID];
    float bo0 = 0.f, bo1 = 0.f;
    if (wid == 0) {
        #pragma unroll
        for (int k = 0; k < HID; ++k)
            w[k] = W_hh[j * HID + k] * (-2.0f * PRESCALE);
    } else {
        const int v0 = 2 * lane, v1 = 2 * lane + 1;
        float s0 = 0.f, s1 = 0.f;
        #pragma unroll
        for (int k = 0; k < HID; ++k) {
            float wa = W_out[v0 * HID + k], wb = W_out[v1 * HID + k];
            s0 += wa; s1 += wb;
            w[k]  = -2.0f * wa;
            wB[k] = -2.0f * wb;
        }
        bo0 = b_out[v0] + s0; bo1 = b_out[v1] + s1;
    }
    __syncthreads();

    // producer pipeline prologue: tokens for steps 0..15, xw for steps 0..7
    float rA = 0.5f, rB = 0.5f;                        // h0 = 0  <=>  r0 = 0.5
    int4 taA, tbA, tcA, tdA, taB, tbB, tcB, tdB;
    float xw0A[4], xw1A[4], xw0B[4], xw1B[4];
    if (wid == 0) {
        __builtin_amdgcn_s_setprio(1);                 // critical-path wave
        taA = *(const int4*)&tokA[0];  tbA = *(const int4*)&tokA[4];
        tcA = *(const int4*)&tokA[8];  tdA = *(const int4*)&tokA[12];
        taB = *(const int4*)&tokB[0];  tbB = *(const int4*)&tokB[4];
        tcB = *(const int4*)&tokB[8];  tdB = *(const int4*)&tokB[12];
        xw0A[0] = Pl[taA.x * HID + j]; xw0A[1] = Pl[taA.y * HID + j];
        xw0A[2] = Pl[taA.z * HID + j]; xw0A[3] = Pl[taA.w * HID + j];
        xw1A[0] = Pl[tbA.x * HID + j]; xw1A[1] = Pl[tbA.y * HID + j];
        xw1A[2] = Pl[tbA.z * HID + j]; xw1A[3] = Pl[tbA.w * HID + j];
        xw0B[0] = Pl[taB.x * HID + j]; xw0B[1] = Pl[taB.y * HID + j];
        xw0B[2] = Pl[taB.z * HID + j]; xw0B[3] = Pl[taB.w * HID + j];
        xw1B[0] = Pl[tbB.x * HID + j]; xw1B[1] = Pl[tbB.y * HID + j];
        xw1B[2] = Pl[tbB.z * HID + j]; xw1B[3] = Pl[tbB.w * HID + j];
    }

    // 33-iteration pipeline: iter c -> wave0 produces chunk c (both rows),
    // waves1-3 consume chunk c-1 from the other LDS buffer half.
    for (int c = 0; c < 33; ++c) {
        if (wid == 0 && c < 32) {
            float* hb = &hbuf[c & 1][0][lane];
            for (int t8 = 0; t8 < 64; t8 += 8) {
                const int t = c * 64 + t8;
                float* hrow = hb + t8 * 64;
                // ---- steps t..t+3 (both rows) ----
                RNN_STEP2(xw0A[0], xw0B[0]); hrow[0 * 64] = loHalf ? rA : rB;
                RNN_STEP2(xw0A[1], xw0B[1]); hrow[1 * 64] = loHalf ? rA : rB;
                RNN_STEP2(xw0A[2], xw0B[2]); hrow[2 * 64] = loHalf ? rA : rB;
                RNN_STEP2(xw0A[3], xw0B[3]); hrow[3 * 64] = loHalf ? rA : rB;
                // refill xw0 for steps t+8..t+11 (latency hidden by next steps)
                float n0A[4] = {Pl[tcA.x * HID + j], Pl[tcA.y * HID + j],
                                Pl[tcA.z * HID + j], Pl[tcA.w * HID + j]};
                tcA = *(const int4*)&tokA[t + 16];
                float n0B[4] = {Pl[tcB.x * HID + j], Pl[tcB.y * HID + j],
                                Pl[tcB.z * HID + j], Pl[tcB.w * HID + j]};
                tcB = *(const int4*)&tokB[t + 16];
                // ---- steps t+4..t+7 (both rows) ----
                RNN_STEP2(xw1A[0], xw1B[0]); hrow[4 * 64] = loHalf ? rA : rB;
                RNN_STEP2(xw1A[1], xw1B[1]); hrow[5 * 64] = loHalf ? rA : rB;
                RNN_STEP2(xw1A[2], xw1B[2]); hrow[6 * 64] = loHalf ? rA : rB;
                RNN_STEP2(xw1A[3], xw1B[3]); hrow[7 * 64] = loHalf ? rA : rB;
                // refill xw1 for steps t+12..t+15
                float n1A[4] = {Pl[tdA.x * HID + j], Pl[tdA.y * HID + j],
                                Pl[tdA.z * HID + j], Pl[tdA.w * HID + j]};
                tdA = *(const int4*)&tokA[t + 20];
                float n1B[4] = {Pl[tdB.x * HID + j], Pl[tdB.y * HID + j],
                                Pl[tdB.z * HID + j], Pl[tdB.w * HID + j]};
                tdB = *(const int4*)&tokB[t + 20];
                #pragma unroll
                for (int u = 0; u < 4; ++u) {
                    xw0A[u] = n0A[u]; xw1A[u] = n1A[u];
                    xw0B[u] = n0B[u]; xw1B[u] = n1B[u];
                }
            }
        }
        if (wid > 0 && c > 0) {
            const int cc = c - 1;
            for (int rr = wid - 1; rr < 128; rr += 3) {
                const int  row = rr & 63;
                const bool isB = rr >= 64;
                const float* hr = &hbuf[cc & 1][row][isB ? 32 : 0];
                const int  bb  = isB ? bB : bA;
                float* op = out + ((size_t)bb * TLEN + (size_t)cc * 64 + row) * VOCAB
                                + 2 * lane;
                float a0 = bo0, a1 = bo1;
                #pragma unroll
                for (int k = 0; k < HID; k += 4) {
                    float4 hv = *(const float4*)(hr + k);   // wave-uniform broadcast
                    a0 = fmaf(hv.x, w[k + 0], a0); a1 = fmaf(hv.x, wB[k + 0], a1);
                    a0 = fmaf(hv.y, w[k + 1], a0); a1 = fmaf(hv.y, wB[k + 1], a1);
                    a0 = fmaf(hv.z, w[k + 2], a0); a1 = fmaf(hv.z, wB[k + 2], a1);
                    a0 = fmaf(hv.w, w[k + 3], a0); a1 = fmaf(hv.w, wB[k + 3], a1);
                }
                *(float2*)op = make_float2(a0, a1);
            }
        }
        __syncthreads();
    }
}

extern "C" void kernel_launch(void* const* d_in, const int* in_sizes, int n_in,
                              void* d_out, int out_size, void* d_ws, size_t ws_size,
                              hipStream_t stream) {
    const int*   inputs = (const int*)  d_in[0];
    const float* emb    = (const float*)d_in[1];
    const float* W_ih   = (const float*)d_in[2];
    const float* W_hh   = (const float*)d_in[3];
    const float* b_ih   = (const float*)d_in[4];
    const float* b_hh   = (const float*)d_in[5];
    const float* W_out  = (const float*)d_in[6];
    const float* b_out  = (const float*)d_in[7];
    float* out = (float*)d_out;

    float* P = (float*)d_ws;   // 10240 B table

    build_table<<<(VOCAB * HID + 255) / 256, 256, 0, stream>>>(emb, W_ih, W_hh,
                                                               b_ih, b_hh, P);
    rnn_fused<<<BATCH / 2, 256, 0, stream>>>(inputs, W_hh, P, W_out, b_out, out);
}